// Round 5
// baseline (231.055 us; speedup 1.0000x reference)
//
#include <hip/hip_runtime.h>
#include <hip/hip_cooperative_groups.h>
#include <math.h>

namespace cg = cooperative_groups;

typedef float f32x4 __attribute__((ext_vector_type(4)));

// ---------------- problem constants ----------------
constexpr int NROWS = 131072;   // N
constexpr int DM    = 256;      // memory width
constexpr int HID   = 200;      // controller hidden
constexpr int ORD   = 262;      // read head out dim
constexpr int OWD   = 774;      // write head out dim
constexpr int NB    = 512;      // fused-kernel blocks; 256 rows each
constexpr float EPSV = 1e-8f;

// d_out layout (floats): out[64] | M_new[N*256] | rw[N] | ww[N] | read[256]
constexpr long long MNEW_OFF = 64;
constexpr long long RW_OFF   = 64LL + (long long)NROWS * DM;
constexpr long long WW_OFF   = RW_OFF + NROWS;
constexpr long long READ_OFF = WW_OFF + NROWS;

// gemv partial scratch inside the (later fully overwritten) M_new region
constexpr long long PART_H_OFF  = MNEW_OFF;            // 16*200
constexpr long long PART_OR_OFF = MNEW_OFF + 4096;     // 25*262
constexpr long long PART_OW_OFF = MNEW_OFF + 16384;    // 25*774

// ws layout (floats), ~22.5 KB total
constexpr int WS_H    = 0;     // h_final[200]
constexpr int WS_KNR  = 256;   // kn_read[256]
constexpr int WS_KNW  = 512;   // kn_write[256]
constexpr int WS_E    = 768;   // erase[256]
constexpr int WS_A    = 1024;  // add[256]
constexpr int WS_SC   = 1280;  // scalars[16]:
// 0 beta_r, 1 g_r, 2..4 s_r, 5 gamma_r, 6 beta_w, 7 g_w, 8..10 s_w, 11 gamma_w,
// 12 sum_r, 13 sum_w, 14 sumwp_r, 15 sumwp_w
constexpr int WS_UBRF = 1536;  // u_r first-row per block [NB]
constexpr int WS_UBRL = 2048;  // u_r last-row per block  [NB]
constexpr int WS_UBWF = 2560;  // u_w first-row per block [NB]
constexpr int WS_UBWL = 3072;  // u_w last-row per block  [NB]
constexpr int WS_RSLAB = 3584; // read-accum slabs [8][256]

__device__ __forceinline__ float softplusf(float x) {
    if (x > 20.0f) return x;
    return logf(1.0f + expf(x));
}
__device__ __forceinline__ float sigmoidf(float x) {
    return 1.0f / (1.0f + expf(-x));
}
__device__ __forceinline__ float dot4(f32x4 a, f32x4 b) {
    return a.x * b.x + a.y * b.y + a.z * b.z + a.w * b.w;
}

// ---------------- K1: h partials: xc @ W1, 16 blocks x 32 rows ----------------
__global__ __launch_bounds__(256) void k1_hpart(
        const float* __restrict__ x, const float* __restrict__ read_prev,
        const float* __restrict__ reads_bias, const float* __restrict__ W1,
        float* __restrict__ part_h) {
    __shared__ float xc[512];
    int t = threadIdx.x;
    xc[t] = x[t];
    xc[256 + t] = read_prev[t] + reads_bias[t];
    __syncthreads();
    if (t < HID) {
        float acc = 0.f;
        int i0 = blockIdx.x * 32;
        #pragma unroll 8
        for (int r = 0; r < 32; ++r)
            acc += xc[i0 + r] * W1[(i0 + r) * HID + t];
        part_h[blockIdx.x * HID + t] = acc;
    }
}

// ---------------- K2: head GEMV partials: h @ {Wr, Ww}, 25 blocks x 8 rows ----
__global__ __launch_bounds__(256) void k2_heads(
        const float* __restrict__ part_h, const float* __restrict__ b1,
        const float* __restrict__ Wr, const float* __restrict__ Ww,
        float* __restrict__ part_or, float* __restrict__ part_ow) {
    __shared__ float h8[8];
    int t = threadIdx.x;
    if (t < 8) {
        int i = blockIdx.x * 8 + t;
        float v = b1[i];
        for (int b = 0; b < 16; ++b) v += part_h[b * HID + i];
        h8[t] = fmaxf(v, 0.f);
    }
    __syncthreads();
    float aor0 = 0.f, aor1 = 0.f, aow0 = 0.f, aow1 = 0.f, aow2 = 0.f, aow3 = 0.f;
    int i0 = blockIdx.x * 8;
    for (int r = 0; r < 8; ++r) {
        float hv = h8[r];
        const float* wr = Wr + (long long)(i0 + r) * ORD;
        const float* wwp = Ww + (long long)(i0 + r) * OWD;
        aor0 += hv * wr[t];
        if (t < 6) aor1 += hv * wr[256 + t];
        aow0 += hv * wwp[t];
        aow1 += hv * wwp[256 + t];
        aow2 += hv * wwp[512 + t];
        if (t < 6) aow3 += hv * wwp[768 + t];
    }
    part_or[blockIdx.x * ORD + t] = aor0;
    if (t < 6) part_or[blockIdx.x * ORD + 256 + t] = aor1;
    float* po = part_ow + blockIdx.x * OWD;
    po[t] = aow0;
    po[256 + t] = aow1;
    po[512 + t] = aow2;
    if (t < 6) po[768 + t] = aow3;
}

// ---------------- K3: finalize heads -> params in ws; zero accumulators ------
__global__ __launch_bounds__(256) void k3_params(
        const float* __restrict__ part_h, const float* __restrict__ b1,
        const float* __restrict__ part_or, const float* __restrict__ br,
        const float* __restrict__ part_ow, const float* __restrict__ bw,
        float* ws) {
    __shared__ float orh[ORD];
    __shared__ float owh[OWD];
    __shared__ float rbuf[8];
    int t = threadIdx.x;
    for (int j = t; j < ORD; j += 256) {
        float v = br[j];
        for (int b = 0; b < 25; ++b) v += part_or[b * ORD + j];
        orh[j] = v;
    }
    for (int j = t; j < OWD; j += 256) {
        float v = bw[j];
        for (int b = 0; b < 25; ++b) v += part_ow[b * OWD + j];
        owh[j] = v;
    }
    if (t < HID) {
        float v = b1[t];
        for (int b = 0; b < 16; ++b) v += part_h[b * HID + t];
        ws[WS_H + t] = fmaxf(v, 0.f);
    }
    // zero read-accum slabs and the 4 global sums
    for (int j = t; j < 2048; j += 256) ws[WS_RSLAB + j] = 0.f;
    if (t < 4) ws[WS_SC + 12 + t] = 0.f;
    __syncthreads();

    float kr = tanhf(orh[t]);
    float kw = tanhf(owh[t]);
    float nr = kr * kr, nw = kw * kw;
    #pragma unroll
    for (int s = 32; s > 0; s >>= 1) {
        nr += __shfl_xor(nr, s, 64);
        nw += __shfl_xor(nw, s, 64);
    }
    int wid = t >> 6, lane = t & 63;
    if (lane == 0) { rbuf[wid] = nr; rbuf[4 + wid] = nw; }
    __syncthreads();
    float normr = sqrtf(rbuf[0] + rbuf[1] + rbuf[2] + rbuf[3]) + EPSV;
    float normw = sqrtf(rbuf[4] + rbuf[5] + rbuf[6] + rbuf[7]) + EPSV;
    ws[WS_KNR + t] = kr / normr;
    ws[WS_KNW + t] = kw / normw;
    ws[WS_E + t] = sigmoidf(owh[262 + t]);
    ws[WS_A + t] = tanhf(owh[518 + t]);
    if (t == 0) {
        ws[WS_SC + 0] = softplusf(orh[256]);
        ws[WS_SC + 1] = sigmoidf(orh[257]);
        float m3 = fmaxf(orh[258], fmaxf(orh[259], orh[260]));
        float e0 = expf(orh[258] - m3), e1 = expf(orh[259] - m3), e2 = expf(orh[260] - m3);
        float es = e0 + e1 + e2;
        ws[WS_SC + 2] = e0 / es; ws[WS_SC + 3] = e1 / es; ws[WS_SC + 4] = e2 / es;
        ws[WS_SC + 5] = 1.0f + softplusf(orh[261]);
        ws[WS_SC + 6] = softplusf(owh[256]);
        ws[WS_SC + 7] = sigmoidf(owh[257]);
        float m3w = fmaxf(owh[258], fmaxf(owh[259], owh[260]));
        float f0 = expf(owh[258] - m3w), f1 = expf(owh[259] - m3w), f2 = expf(owh[260] - m3w);
        float fs = f0 + f1 + f2;
        ws[WS_SC + 8] = f0 / fs; ws[WS_SC + 9] = f1 / fs; ws[WS_SC + 10] = f2 / fs;
        ws[WS_SC + 11] = 1.0f + softplusf(owh[261]);
    }
}

// ---------------- fused M-pipeline: scores | shift+pow | update ---------------
// 512 blocks x 256 threads, cooperative. Block b owns rows [b*256, b*256+256).
// u and wp live in LDS across the two grid syncs.
__global__ __launch_bounds__(256, 2) void k_fused(
        const float* __restrict__ M, float* ws, float* dout,
        const float* __restrict__ read_w, const float* __restrict__ write_w) {
    cg::grid_group grid = cg::this_grid();
    __shared__ float lds_ur[256], lds_uw[256], lds_wpr[256], lds_wpw[256];
    __shared__ float redbuf[4][256];
    __shared__ float sbuf[8];
    const int t = threadIdx.x, lane = t & 63, wid = t >> 6;
    const int b = blockIdx.x;
    const int base = b * 256;

    // ---------- phase 1: content scores -> u (LDS), global sums ----------
    {
        const int lp = lane & 15, sub = lane >> 4;   // 16 lanes/row, 4 rows/iter
        f32x4 knr[4], knw[4];
        #pragma unroll
        for (int j = 0; j < 4; ++j) {
            knr[j] = *(const f32x4*)(ws + WS_KNR + j * 64 + lp * 4);
            knw[j] = *(const f32x4*)(ws + WS_KNW + j * 64 + lp * 4);
        }
        const float beta_r = ws[WS_SC + 0], beta_w = ws[WS_SC + 6];
        const int n0 = base + wid * 64;
        const float* mb = M + (long long)n0 * DM;
        float sr = 0.f, sw = 0.f;
        #pragma unroll 4
        for (int i = 0; i < 16; ++i) {
            int row = i * 4 + sub;
            const float* rp = mb + row * DM + lp * 4;
            f32x4 a0 = *(const f32x4*)(rp);
            f32x4 a1 = *(const f32x4*)(rp + 64);
            f32x4 a2 = *(const f32x4*)(rp + 128);
            f32x4 a3 = *(const f32x4*)(rp + 192);
            float nn = dot4(a0, a0) + dot4(a1, a1) + dot4(a2, a2) + dot4(a3, a3);
            float dr = dot4(a0, knr[0]) + dot4(a1, knr[1]) + dot4(a2, knr[2]) + dot4(a3, knr[3]);
            float dw = dot4(a0, knw[0]) + dot4(a1, knw[1]) + dot4(a2, knw[2]) + dot4(a3, knw[3]);
            #pragma unroll
            for (int s = 1; s <= 8; s <<= 1) {
                nn += __shfl_xor(nn, s, 64);
                dr += __shfl_xor(dr, s, 64);
                dw += __shfl_xor(dw, s, 64);
            }
            float rn = 1.0f / (sqrtf(nn) + EPSV);
            // exp(beta*(cos-1)) == stabilized softmax numerator (cos <= 1)
            float ur = expf(beta_r * (dr * rn - 1.0f));
            float uw = expf(beta_w * (dw * rn - 1.0f));
            if (lp == 0) { lds_ur[wid * 64 + row] = ur; lds_uw[wid * 64 + row] = uw; }
            sr += ur; sw += uw;   // identical across the 16-lane group
        }
        // sum across the 4 groups (values within a group are duplicates)
        sr += __shfl_xor(sr, 16, 64); sr += __shfl_xor(sr, 32, 64);
        sw += __shfl_xor(sw, 16, 64); sw += __shfl_xor(sw, 32, 64);
        if (lane == 0) { sbuf[wid] = sr; sbuf[4 + wid] = sw; }
        __syncthreads();
        if (t == 0) {
            atomicAdd(&ws[WS_SC + 12], sbuf[0] + sbuf[1] + sbuf[2] + sbuf[3]);
            atomicAdd(&ws[WS_SC + 13], sbuf[4] + sbuf[5] + sbuf[6] + sbuf[7]);
            // publish boundary rows for neighbor blocks' shift conv
            ws[WS_UBRF + b] = lds_ur[0]; ws[WS_UBRL + b] = lds_ur[255];
            ws[WS_UBWF + b] = lds_uw[0]; ws[WS_UBWL + b] = lds_uw[255];
        }
    }
    grid.sync();

    // ---------- phase 2: gate + circular shift + pow -> wp (LDS), sums ----
    {
        const float g_r = ws[WS_SC + 1], g_w = ws[WS_SC + 7];
        const float sr0 = ws[WS_SC + 2], sr1 = ws[WS_SC + 3], sr2 = ws[WS_SC + 4];
        const float sw0 = ws[WS_SC + 8], sw1 = ws[WS_SC + 9], sw2 = ws[WS_SC + 10];
        const float gam_r = ws[WS_SC + 5], gam_w = ws[WS_SC + 11];
        const float isr = g_r / ws[WS_SC + 12], isw = g_w / ws[WS_SC + 13];
        const float omg_r = 1.f - g_r, omg_w = 1.f - g_w;
        int n = base + t;
        int nm = (n == 0) ? NROWS - 1 : n - 1;
        int np = (n == NROWS - 1) ? 0 : n + 1;
        float urm = (t == 0)   ? ws[WS_UBRL + (b + NB - 1) % NB] : lds_ur[t - 1];
        float ur0 = lds_ur[t];
        float urp = (t == 255) ? ws[WS_UBRF + (b + 1) % NB]      : lds_ur[t + 1];
        float uwm = (t == 0)   ? ws[WS_UBWL + (b + NB - 1) % NB] : lds_uw[t - 1];
        float uw0 = lds_uw[t];
        float uwp = (t == 255) ? ws[WS_UBWF + (b + 1) % NB]      : lds_uw[t + 1];
        float wgm = urm * isr + omg_r * read_w[nm];
        float wg0 = ur0 * isr + omg_r * read_w[n];
        float wgp = urp * isr + omg_r * read_w[np];
        float wt = sr0 * wgp + sr1 * wg0 + sr2 * wgm;
        float wpr = powf(wt, gam_r);
        float vgm = uwm * isw + omg_w * write_w[nm];
        float vg0 = uw0 * isw + omg_w * write_w[n];
        float vgp = uwp * isw + omg_w * write_w[np];
        float vt = sw0 * vgp + sw1 * vg0 + sw2 * vgm;
        float wpw = powf(vt, gam_w);
        lds_wpr[t] = wpr; lds_wpw[t] = wpw;
        float lr = wpr, lw = wpw;
        #pragma unroll
        for (int s = 1; s <= 32; s <<= 1) {
            lr += __shfl_xor(lr, s, 64);
            lw += __shfl_xor(lw, s, 64);
        }
        if (lane == 0) { sbuf[wid] = lr; sbuf[4 + wid] = lw; }
        __syncthreads();
        if (t == 0) {
            atomicAdd(&ws[WS_SC + 14], sbuf[0] + sbuf[1] + sbuf[2] + sbuf[3]);
            atomicAdd(&ws[WS_SC + 15], sbuf[4] + sbuf[5] + sbuf[6] + sbuf[7]);
        }
    }
    grid.sync();

    // ---------- phase 3: normalize, M_new (nt stores), read partials ------
    {
        const f32x4 e4 = *(const f32x4*)(ws + WS_E + lane * 4);
        const f32x4 a4 = *(const f32x4*)(ws + WS_A + lane * 4);
        const float inv_r = 1.0f / (ws[WS_SC + 14] + EPSV);
        const float inv_w = 1.0f / (ws[WS_SC + 15] + EPSV);
        const int n0 = base + wid * 64;
        const float* mb = M + (long long)n0 * DM + lane * 4;
        float* ob = dout + MNEW_OFF + (long long)n0 * DM + lane * 4;
        const float* wpr = &lds_wpr[wid * 64];
        const float* wpw = &lds_wpw[wid * 64];
        f32x4 acc = {0.f, 0.f, 0.f, 0.f};
        #pragma unroll 8
        for (int r = 0; r < 64; ++r) {
            float rwv = wpr[r] * inv_r;   // LDS broadcast
            float wwv = wpw[r] * inv_w;
            f32x4 m = *(const f32x4*)(mb + (long long)r * DM);
            f32x4 o;
            acc.x += rwv * m.x; acc.y += rwv * m.y;
            acc.z += rwv * m.z; acc.w += rwv * m.w;
            o.x = m.x * (1.0f - wwv * e4.x) + wwv * a4.x;
            o.y = m.y * (1.0f - wwv * e4.y) + wwv * a4.y;
            o.z = m.z * (1.0f - wwv * e4.z) + wwv * a4.z;
            o.w = m.w * (1.0f - wwv * e4.w) + wwv * a4.w;
            __builtin_nontemporal_store(o, (f32x4*)(ob + (long long)r * DM));
        }
        // final normalized weights (coalesced)
        dout[RW_OFF + base + t] = lds_wpr[t] * inv_r;
        dout[WW_OFF + base + t] = lds_wpw[t] * inv_w;
        // read partials -> 8 slabs (64-way contention instead of 512)
        *(f32x4*)(&redbuf[wid][lane * 4]) = acc;
        __syncthreads();
        float s = redbuf[0][t] + redbuf[1][t] + redbuf[2][t] + redbuf[3][t];
        atomicAdd(&ws[WS_RSLAB + (b & 7) * 256 + t], s);
    }
}

// ---------------- K7: read finalize + output MLP epilogue --------------------
__global__ __launch_bounds__(256) void k7_out(
        const float* ws, const float* __restrict__ Wo1, const float* __restrict__ bo1,
        const float* __restrict__ Wo2, const float* __restrict__ bo2, float* dout) {
    __shared__ float c[456];
    __shared__ float h2[100];
    int t = threadIdx.x;
    float rv = 0.f;
    #pragma unroll
    for (int k = 0; k < 8; ++k) rv += ws[WS_RSLAB + k * 256 + t];
    dout[READ_OFF + t] = rv;
    if (t < HID) c[t] = ws[WS_H + t];
    c[200 + t] = rv;
    __syncthreads();
    if (t < 100) {
        float acc = bo1[t];
        #pragma unroll 8
        for (int i = 0; i < 456; ++i) acc += c[i] * Wo1[i * 100 + t];
        h2[t] = fmaxf(acc, 0.f);
    }
    __syncthreads();
    if (t < 64) {
        float acc = bo2[t];
        #pragma unroll
        for (int i = 0; i < 100; ++i) acc += h2[i] * Wo2[i * 64 + t];
        dout[t] = acc;
    }
}

extern "C" void kernel_launch(void* const* d_in, const int* in_sizes, int n_in,
                              void* d_out, int out_size, void* d_ws, size_t ws_size,
                              hipStream_t stream) {
    const float* x          = (const float*)d_in[0];
    const float* M          = (const float*)d_in[1];
    const float* read_w     = (const float*)d_in[2];
    const float* write_w    = (const float*)d_in[3];
    const float* read_prev  = (const float*)d_in[4];
    const float* reads_bias = (const float*)d_in[5];
    const float* W1  = (const float*)d_in[6];
    const float* b1  = (const float*)d_in[7];
    const float* Wr  = (const float*)d_in[8];
    const float* br  = (const float*)d_in[9];
    const float* Ww  = (const float*)d_in[10];
    const float* bw  = (const float*)d_in[11];
    const float* Wo1 = (const float*)d_in[12];
    const float* bo1 = (const float*)d_in[13];
    const float* Wo2 = (const float*)d_in[14];
    const float* bo2 = (const float*)d_in[15];
    float* dout = (float*)d_out;
    float* ws   = (float*)d_ws;

    float* part_h  = dout + PART_H_OFF;
    float* part_or = dout + PART_OR_OFF;
    float* part_ow = dout + PART_OW_OFF;

    k1_hpart<<<16, 256, 0, stream>>>(x, read_prev, reads_bias, W1, part_h);
    k2_heads<<<25, 256, 0, stream>>>(part_h, b1, Wr, Ww, part_or, part_ow);
    k3_params<<<1, 256, 0, stream>>>(part_h, b1, part_or, br, part_ow, bw, ws);

    void* args[5];
    args[0] = (void*)&M;
    args[1] = (void*)&ws;
    args[2] = (void*)&dout;
    args[3] = (void*)&read_w;
    args[4] = (void*)&write_w;
    hipLaunchCooperativeKernel(k_fused, dim3(NB), dim3(256), args, 0u, stream);

    k7_out<<<1, 256, 0, stream>>>(ws, Wo1, bo1, Wo2, bo2, dout);
}

// Round 6
// 118.409 us; speedup vs baseline: 1.9513x; 1.9513x over previous
//
#include <hip/hip_runtime.h>
#include <math.h>

typedef float f32x4 __attribute__((ext_vector_type(4)));

// ---------------- problem constants ----------------
constexpr int NROWS = 131072;   // N
constexpr int DM    = 256;      // memory width
constexpr int HID   = 200;      // controller hidden
constexpr int ORD   = 262;      // read head out dim
constexpr int OWD   = 774;      // write head out dim
constexpr float EPSV = 1e-8f;

// d_out layout (floats): out[64] | M_new[N*256] | rw[N] | ww[N] | read[256]
constexpr long long MNEW_OFF = 64;
constexpr long long RW_OFF   = 64LL + (long long)NROWS * DM;
constexpr long long WW_OFF   = RW_OFF + NROWS;
constexpr long long READ_OFF = WW_OFF + NROWS;

// big scratch inside the (later fully overwritten) M_new region
constexpr long long U_R_OFF   = MNEW_OFF;                       // N floats
constexpr long long U_W_OFF   = MNEW_OFF + NROWS;               // N floats
constexpr long long PART_H_OFF  = MNEW_OFF + 2LL * NROWS;           // 16*200
constexpr long long PART_OR_OFF = MNEW_OFF + 2LL * NROWS + 4096;    // 25*262
constexpr long long PART_OW_OFF = MNEW_OFF + 2LL * NROWS + 16384;   // 25*774

// ws layout (floats), ~22.5 KB
constexpr int WS_H    = 0;     // h_final[200]
constexpr int WS_KNR  = 256;   // kn_read[256]
constexpr int WS_KNW  = 512;   // kn_write[256]
constexpr int WS_E    = 768;   // erase[256]
constexpr int WS_A    = 1024;  // add[256]
constexpr int WS_SC   = 1280;  // head params[12]:
// 0 beta_r, 1 g_r, 2..4 s_r, 5 gamma_r, 6 beta_w, 7 g_w, 8..10 s_w, 11 gamma_w
constexpr int WS_PS   = 1312;  // partial-sum slabs [16][4]: {sum_r, sum_w, sumwp_r, sumwp_w}
constexpr int WS_RSLAB = 1536; // read-accum slabs [16][256]

__device__ __forceinline__ float softplusf(float x) {
    if (x > 20.0f) return x;
    return logf(1.0f + expf(x));
}
__device__ __forceinline__ float sigmoidf(float x) {
    return 1.0f / (1.0f + expf(-x));
}
__device__ __forceinline__ float dot4(f32x4 a, f32x4 b) {
    return a.x * b.x + a.y * b.y + a.z * b.z + a.w * b.w;
}

// ---------------- K1: h partials: xc @ W1, 16 blocks x 32 rows ----------------
__global__ __launch_bounds__(256) void k1_hpart(
        const float* __restrict__ x, const float* __restrict__ read_prev,
        const float* __restrict__ reads_bias, const float* __restrict__ W1,
        float* __restrict__ part_h) {
    __shared__ float xc[512];
    int t = threadIdx.x;
    xc[t] = x[t];
    xc[256 + t] = read_prev[t] + reads_bias[t];
    __syncthreads();
    if (t < HID) {
        float acc = 0.f;
        int i0 = blockIdx.x * 32;
        #pragma unroll 8
        for (int r = 0; r < 32; ++r)
            acc += xc[i0 + r] * W1[(i0 + r) * HID + t];
        part_h[blockIdx.x * HID + t] = acc;
    }
}

// ---------------- K2: head GEMV partials: h @ {Wr, Ww}, 25 blocks x 8 rows ----
__global__ __launch_bounds__(256) void k2_heads(
        const float* __restrict__ part_h, const float* __restrict__ b1,
        const float* __restrict__ Wr, const float* __restrict__ Ww,
        float* __restrict__ part_or, float* __restrict__ part_ow) {
    __shared__ float h8[8];
    int t = threadIdx.x;
    if (t < 8) {
        int i = blockIdx.x * 8 + t;
        float v = b1[i];
        for (int b = 0; b < 16; ++b) v += part_h[b * HID + i];
        h8[t] = fmaxf(v, 0.f);
    }
    __syncthreads();
    float aor0 = 0.f, aor1 = 0.f, aow0 = 0.f, aow1 = 0.f, aow2 = 0.f, aow3 = 0.f;
    int i0 = blockIdx.x * 8;
    for (int r = 0; r < 8; ++r) {
        float hv = h8[r];
        const float* wr = Wr + (long long)(i0 + r) * ORD;
        const float* wwp = Ww + (long long)(i0 + r) * OWD;
        aor0 += hv * wr[t];
        if (t < 6) aor1 += hv * wr[256 + t];
        aow0 += hv * wwp[t];
        aow1 += hv * wwp[256 + t];
        aow2 += hv * wwp[512 + t];
        if (t < 6) aow3 += hv * wwp[768 + t];
    }
    part_or[blockIdx.x * ORD + t] = aor0;
    if (t < 6) part_or[blockIdx.x * ORD + 256 + t] = aor1;
    float* po = part_ow + blockIdx.x * OWD;
    po[t] = aow0;
    po[256 + t] = aow1;
    po[512 + t] = aow2;
    if (t < 6) po[768 + t] = aow3;
}

// ---------------- K3: finalize heads -> params in ws; zero slabs -------------
__global__ __launch_bounds__(256) void k3_params(
        const float* __restrict__ part_h, const float* __restrict__ b1,
        const float* __restrict__ part_or, const float* __restrict__ br,
        const float* __restrict__ part_ow, const float* __restrict__ bw,
        float* ws) {
    __shared__ float orh[ORD];
    __shared__ float owh[OWD];
    __shared__ float rbuf[8];
    int t = threadIdx.x;
    for (int j = t; j < ORD; j += 256) {
        float v = br[j];
        for (int b = 0; b < 25; ++b) v += part_or[b * ORD + j];
        orh[j] = v;
    }
    for (int j = t; j < OWD; j += 256) {
        float v = bw[j];
        for (int b = 0; b < 25; ++b) v += part_ow[b * OWD + j];
        owh[j] = v;
    }
    if (t < HID) {
        float v = b1[t];
        for (int b = 0; b < 16; ++b) v += part_h[b * HID + t];
        ws[WS_H + t] = fmaxf(v, 0.f);
    }
    // zero partial-sum slabs (64) and read-accum slabs (16*256)
    for (int j = t; j < 64; j += 256) ws[WS_PS + j] = 0.f;
    for (int j = t; j < 4096; j += 256) ws[WS_RSLAB + j] = 0.f;
    __syncthreads();

    float kr = tanhf(orh[t]);
    float kw = tanhf(owh[t]);
    float nr = kr * kr, nw = kw * kw;
    #pragma unroll
    for (int s = 32; s > 0; s >>= 1) {
        nr += __shfl_xor(nr, s, 64);
        nw += __shfl_xor(nw, s, 64);
    }
    int wid = t >> 6, lane = t & 63;
    if (lane == 0) { rbuf[wid] = nr; rbuf[4 + wid] = nw; }
    __syncthreads();
    float normr = sqrtf(rbuf[0] + rbuf[1] + rbuf[2] + rbuf[3]) + EPSV;
    float normw = sqrtf(rbuf[4] + rbuf[5] + rbuf[6] + rbuf[7]) + EPSV;
    ws[WS_KNR + t] = kr / normr;
    ws[WS_KNW + t] = kw / normw;
    ws[WS_E + t] = sigmoidf(owh[262 + t]);
    ws[WS_A + t] = tanhf(owh[518 + t]);
    if (t == 0) {
        ws[WS_SC + 0] = softplusf(orh[256]);
        ws[WS_SC + 1] = sigmoidf(orh[257]);
        float m3 = fmaxf(orh[258], fmaxf(orh[259], orh[260]));
        float e0 = expf(orh[258] - m3), e1 = expf(orh[259] - m3), e2 = expf(orh[260] - m3);
        float es = e0 + e1 + e2;
        ws[WS_SC + 2] = e0 / es; ws[WS_SC + 3] = e1 / es; ws[WS_SC + 4] = e2 / es;
        ws[WS_SC + 5] = 1.0f + softplusf(orh[261]);
        ws[WS_SC + 6] = softplusf(owh[256]);
        ws[WS_SC + 7] = sigmoidf(owh[257]);
        float m3w = fmaxf(owh[258], fmaxf(owh[259], owh[260]));
        float f0 = expf(owh[258] - m3w), f1 = expf(owh[259] - m3w), f2 = expf(owh[260] - m3w);
        float fs = f0 + f1 + f2;
        ws[WS_SC + 8] = f0 / fs; ws[WS_SC + 9] = f1 / fs; ws[WS_SC + 10] = f2 / fs;
        ws[WS_SC + 11] = 1.0f + softplusf(owh[261]);
    }
}

// ---------------- K4: M pass 1 — content scores -> u, slab sums --------------
// 2048 blocks x 4 waves x 16 rows/wave. 16 lanes/row, 4 rows in flight.
__global__ __launch_bounds__(256) void k4_scores(
        const float* __restrict__ M, float* ws,
        float* __restrict__ u_r, float* __restrict__ u_w) {
    __shared__ float sbuf[8];
    int t = threadIdx.x, lane = t & 63, wid = t >> 6;
    const int lp = lane & 15, sub = lane >> 4;   // column-group, row-in-flight
    f32x4 knr[4], knw[4];
    #pragma unroll
    for (int j = 0; j < 4; ++j) {
        knr[j] = *(const f32x4*)(ws + WS_KNR + j * 64 + lp * 4);
        knw[j] = *(const f32x4*)(ws + WS_KNW + j * 64 + lp * 4);
    }
    const float beta_r = ws[WS_SC + 0], beta_w = ws[WS_SC + 6];
    const int n0 = blockIdx.x * 64 + wid * 16;
    const float* mb = M + (long long)n0 * DM;
    float sr = 0.f, sw = 0.f, uval = 0.f;
    const int lr_ = lane & 15;
    const int my_i = lr_ >> 2;          // iteration producing my target row
    const int src = (lr_ & 3) * 16;     // lane group holding that row
    #pragma unroll
    for (int i = 0; i < 4; ++i) {
        const float* rp = mb + (i * 4 + sub) * DM + lp * 4;
        f32x4 a0 = *(const f32x4*)(rp);
        f32x4 a1 = *(const f32x4*)(rp + 64);
        f32x4 a2 = *(const f32x4*)(rp + 128);
        f32x4 a3 = *(const f32x4*)(rp + 192);
        float nn = dot4(a0, a0) + dot4(a1, a1) + dot4(a2, a2) + dot4(a3, a3);
        float dr = dot4(a0, knr[0]) + dot4(a1, knr[1]) + dot4(a2, knr[2]) + dot4(a3, knr[3]);
        float dw = dot4(a0, knw[0]) + dot4(a1, knw[1]) + dot4(a2, knw[2]) + dot4(a3, knw[3]);
        #pragma unroll
        for (int s = 1; s <= 8; s <<= 1) {
            nn += __shfl_xor(nn, s, 64);
            dr += __shfl_xor(dr, s, 64);
            dw += __shfl_xor(dw, s, 64);
        }
        float rn = 1.0f / (sqrtf(nn) + EPSV);
        // exp(beta*(cos-1)) == stabilized softmax numerator (cos <= 1)
        float ur = expf(beta_r * (dr * rn - 1.0f));
        float uw = expf(beta_w * (dw * rn - 1.0f));
        sr += ur; sw += uw;   // identical across each 16-lane group
        float vr = __shfl(ur, src, 64);
        float vw = __shfl(uw, src, 64);
        if (i == my_i) uval = (lane < 16) ? vr : vw;
    }
    if (lane < 16)       u_r[n0 + lane] = uval;
    else if (lane < 32)  u_w[n0 + lane - 16] = uval;
    // cross-group sum (groups hold disjoint row subsets)
    sr += __shfl_xor(sr, 16, 64); sr += __shfl_xor(sr, 32, 64);
    sw += __shfl_xor(sw, 16, 64); sw += __shfl_xor(sw, 32, 64);
    if (lane == 0) { sbuf[wid] = sr; sbuf[4 + wid] = sw; }
    __syncthreads();
    if (t == 0) {
        float* ps = ws + WS_PS + (blockIdx.x & 15) * 4;
        atomicAdd(&ps[0], sbuf[0] + sbuf[1] + sbuf[2] + sbuf[3]);
        atomicAdd(&ps[1], sbuf[4] + sbuf[5] + sbuf[6] + sbuf[7]);
    }
}

// ---------------- K5: gate + circular shift + pow, slab sums -----------------
// 512 blocks x 256 threads, one row per thread.
__global__ __launch_bounds__(256) void k5_shift(
        const float* __restrict__ u_r, const float* __restrict__ u_w,
        const float* __restrict__ read_w, const float* __restrict__ write_w,
        float* ws, float* __restrict__ wp_r, float* __restrict__ wp_w) {
    __shared__ float sbuf[8];
    int t = threadIdx.x;
    int n = blockIdx.x * 256 + t;
    float sum_r = 0.f, sum_w = 0.f;
    #pragma unroll
    for (int k = 0; k < 16; ++k) {
        sum_r += ws[WS_PS + k * 4 + 0];
        sum_w += ws[WS_PS + k * 4 + 1];
    }
    float g_r = ws[WS_SC + 1], g_w = ws[WS_SC + 7];
    float omg_r = 1.f - g_r, omg_w = 1.f - g_w;
    float sr0 = ws[WS_SC + 2], sr1 = ws[WS_SC + 3], sr2 = ws[WS_SC + 4];
    float sw0 = ws[WS_SC + 8], sw1 = ws[WS_SC + 9], sw2 = ws[WS_SC + 10];
    float gam_r = ws[WS_SC + 5], gam_w = ws[WS_SC + 11];
    float isr = g_r / sum_r;   // fold gate into softmax scale
    float isw = g_w / sum_w;
    int nm = (n == 0) ? NROWS - 1 : n - 1;
    int np = (n == NROWS - 1) ? 0 : n + 1;
    float wgm = u_r[nm] * isr + omg_r * read_w[nm];
    float wg0 = u_r[n]  * isr + omg_r * read_w[n];
    float wgp = u_r[np] * isr + omg_r * read_w[np];
    float wt = sr0 * wgp + sr1 * wg0 + sr2 * wgm;
    float wpr = powf(wt, gam_r);
    wp_r[n] = wpr;
    float vgm = u_w[nm] * isw + omg_w * write_w[nm];
    float vg0 = u_w[n]  * isw + omg_w * write_w[n];
    float vgp = u_w[np] * isw + omg_w * write_w[np];
    float vt = sw0 * vgp + sw1 * vg0 + sw2 * vgm;
    float wpw = powf(vt, gam_w);
    wp_w[n] = wpw;
    float lr = wpr, lw = wpw;
    #pragma unroll
    for (int s = 1; s <= 32; s <<= 1) {
        lr += __shfl_xor(lr, s, 64);
        lw += __shfl_xor(lw, s, 64);
    }
    int wid = t >> 6, lane = t & 63;
    if (lane == 0) { sbuf[wid] = lr; sbuf[4 + wid] = lw; }
    __syncthreads();
    if (t == 0) {
        float* ps = ws + WS_PS + (blockIdx.x & 15) * 4;
        atomicAdd(&ps[2], sbuf[0] + sbuf[1] + sbuf[2] + sbuf[3]);
        atomicAdd(&ps[3], sbuf[4] + sbuf[5] + sbuf[6] + sbuf[7]);
    }
}

// ---------------- K6: M pass 2 — rw/ww finalize, M_new (nt), read slabs ------
// 2048 blocks x 4 waves x 16 rows/wave.
__global__ __launch_bounds__(256) void k6_update(
        const float* __restrict__ M, float* ws, float* dout) {
    __shared__ float redbuf[4][256];
    int t = threadIdx.x, lane = t & 63, wid = t >> 6;
    const f32x4 e4 = *(const f32x4*)(ws + WS_E + lane * 4);
    const f32x4 a4 = *(const f32x4*)(ws + WS_A + lane * 4);
    float swp_r = 0.f, swp_w = 0.f;
    #pragma unroll
    for (int k = 0; k < 16; ++k) {
        swp_r += ws[WS_PS + k * 4 + 2];
        swp_w += ws[WS_PS + k * 4 + 3];
    }
    const float inv_r = 1.0f / (swp_r + EPSV);
    const float inv_w = 1.0f / (swp_w + EPSV);
    float* rw  = dout + RW_OFF;      // holds wp_r on entry
    float* wwb = dout + WW_OFF;      // holds wp_w on entry
    const int n0 = blockIdx.x * 64 + wid * 16;
    // lanes 0-15: wp_r rows, lanes 16-31: wp_w rows
    float wpv = (lane < 16) ? rw[n0 + lane]
              : (lane < 32) ? wwb[n0 + lane - 16] : 0.f;
    const float* mb = M + (long long)n0 * DM + lane * 4;
    float* ob = dout + MNEW_OFF + (long long)n0 * DM + lane * 4;
    f32x4 acc = {0.f, 0.f, 0.f, 0.f};
    #pragma unroll 8
    for (int r = 0; r < 16; ++r) {
        float rwv = __shfl(wpv, r, 64) * inv_r;
        float wwv = __shfl(wpv, 16 + r, 64) * inv_w;
        f32x4 m = *(const f32x4*)(mb + (long long)r * DM);
        f32x4 o;
        acc.x += rwv * m.x; acc.y += rwv * m.y;
        acc.z += rwv * m.z; acc.w += rwv * m.w;
        o.x = m.x * (1.0f - wwv * e4.x) + wwv * a4.x;
        o.y = m.y * (1.0f - wwv * e4.y) + wwv * a4.y;
        o.z = m.z * (1.0f - wwv * e4.z) + wwv * a4.z;
        o.w = m.w * (1.0f - wwv * e4.w) + wwv * a4.w;
        __builtin_nontemporal_store(o, (f32x4*)(ob + (long long)r * DM));
    }
    // normalized weights back (after all wp reads in this block's range)
    if (lane < 16)      rw[n0 + lane] = wpv * inv_r;
    else if (lane < 32) wwb[n0 + lane - 16] = wpv * inv_w;
    *(f32x4*)(&redbuf[wid][lane * 4]) = acc;
    __syncthreads();
    float s = redbuf[0][t] + redbuf[1][t] + redbuf[2][t] + redbuf[3][t];
    atomicAdd(&ws[WS_RSLAB + (blockIdx.x & 15) * 256 + t], s);
}

// ---------------- K7: read finalize + output MLP epilogue --------------------
__global__ __launch_bounds__(256) void k7_out(
        const float* ws, const float* __restrict__ Wo1, const float* __restrict__ bo1,
        const float* __restrict__ Wo2, const float* __restrict__ bo2, float* dout) {
    __shared__ float c[456];
    __shared__ float h2[100];
    int t = threadIdx.x;
    float rv = 0.f;
    #pragma unroll
    for (int k = 0; k < 16; ++k) rv += ws[WS_RSLAB + k * 256 + t];
    dout[READ_OFF + t] = rv;
    if (t < HID) c[t] = ws[WS_H + t];
    c[200 + t] = rv;
    __syncthreads();
    if (t < 100) {
        float acc = bo1[t];
        #pragma unroll 8
        for (int i = 0; i < 456; ++i) acc += c[i] * Wo1[i * 100 + t];
        h2[t] = fmaxf(acc, 0.f);
    }
    __syncthreads();
    if (t < 64) {
        float acc = bo2[t];
        #pragma unroll
        for (int i = 0; i < 100; ++i) acc += h2[i] * Wo2[i * 64 + t];
        dout[t] = acc;
    }
}

extern "C" void kernel_launch(void* const* d_in, const int* in_sizes, int n_in,
                              void* d_out, int out_size, void* d_ws, size_t ws_size,
                              hipStream_t stream) {
    const float* x          = (const float*)d_in[0];
    const float* M          = (const float*)d_in[1];
    const float* read_w     = (const float*)d_in[2];
    const float* write_w    = (const float*)d_in[3];
    const float* read_prev  = (const float*)d_in[4];
    const float* reads_bias = (const float*)d_in[5];
    const float* W1  = (const float*)d_in[6];
    const float* b1  = (const float*)d_in[7];
    const float* Wr  = (const float*)d_in[8];
    const float* br  = (const float*)d_in[9];
    const float* Ww  = (const float*)d_in[10];
    const float* bw  = (const float*)d_in[11];
    const float* Wo1 = (const float*)d_in[12];
    const float* bo1 = (const float*)d_in[13];
    const float* Wo2 = (const float*)d_in[14];
    const float* bo2 = (const float*)d_in[15];
    float* dout = (float*)d_out;
    float* ws   = (float*)d_ws;

    float* part_h  = dout + PART_H_OFF;
    float* part_or = dout + PART_OR_OFF;
    float* part_ow = dout + PART_OW_OFF;
    float* u_r = dout + U_R_OFF;
    float* u_w = dout + U_W_OFF;

    k1_hpart<<<16, 256, 0, stream>>>(x, read_prev, reads_bias, W1, part_h);
    k2_heads<<<25, 256, 0, stream>>>(part_h, b1, Wr, Ww, part_or, part_ow);
    k3_params<<<1, 256, 0, stream>>>(part_h, b1, part_or, br, part_ow, bw, ws);
    k4_scores<<<2048, 256, 0, stream>>>(M, ws, u_r, u_w);
    k5_shift<<<512, 256, 0, stream>>>(u_r, u_w, read_w, write_w, ws,
                                      dout + RW_OFF, dout + WW_OFF);
    k6_update<<<2048, 256, 0, stream>>>(M, ws, dout);
    k7_out<<<1, 256, 0, stream>>>(ws, Wo1, bo1, Wo2, bo2, dout);
}